// Round 1
// baseline (6198.010 us; speedup 1.0000x reference)
//
#include <hip/hip_runtime.h>
#include <float.h>
#include <math.h>

#define DIM 512
#define EPSN 1e-12f

// ---------------- wave (64-lane) sum ----------------
__device__ inline float wave_sum(float v) {
#pragma unroll
  for (int o = 32; o > 0; o >>= 1) v += __shfl_xor(v, o, 64);
  return v;
}

// one wave per emb row: eepair[j] = { sum(embn^2), 1/max(||emb_j||,eps) }
__global__ __launch_bounds__(256) void emb_norm_kernel(
    const float* __restrict__ emb, float2* __restrict__ eepair) {
  int row = blockIdx.x * 4 + (threadIdx.x >> 6);
  int lane = threadIdx.x & 63;
  const float* p = emb + (size_t)row * DIM;
  float x[8];
  float ss = 0.f;
#pragma unroll
  for (int i = 0; i < 8; ++i) { x[i] = p[i * 64 + lane]; ss += x[i] * x[i]; }
  ss = wave_sum(ss);
  float d = fmaxf(sqrtf(ss), EPSN);
  float ee = 0.f;
#pragma unroll
  for (int i = 0; i < 8; ++i) { float y = x[i] / d; ee += y * y; }
  ee = wave_sum(ee);
  if (lane == 0) eepair[row] = make_float2(ee, 1.0f / d);
}

// one wave per z row: zinv[n] = 1/max(||z_n||,eps)
__global__ __launch_bounds__(256) void z_norm_kernel(
    const float* __restrict__ z, float* __restrict__ zinv) {
  int row = blockIdx.x * 4 + (threadIdx.x >> 6);
  int lane = threadIdx.x & 63;
  const float* p = z + (size_t)row * DIM;
  float ss = 0.f;
#pragma unroll
  for (int i = 0; i < 8; ++i) { float v = p[i * 64 + lane]; ss += v * v; }
  ss = wave_sum(ss);
  if (lane == 0) zinv[row] = 1.0f / fmaxf(sqrtf(ss), EPSN);
}

// ---------------- distance + argmin ----------------
// Block: 256 threads = (tx 0..31, ty 0..7). TM=32 rows, TN=128 codes/tile,
// BK=32. Micro-tile 4 rows x 4 codes per thread. fp32 for argmin fidelity.
#define TM 32
#define TN 128
#define BK 32

#define ROWFMA(AV, I)                                                     \
  acc[I][0] += AV.x * b0.x + AV.y * b1.x + AV.z * b2.x + AV.w * b3.x;     \
  acc[I][1] += AV.x * b0.y + AV.y * b1.y + AV.z * b2.y + AV.w * b3.y;     \
  acc[I][2] += AV.x * b0.z + AV.y * b1.z + AV.z * b2.z + AV.w * b3.z;     \
  acc[I][3] += AV.x * b0.w + AV.y * b1.w + AV.z * b2.w + AV.w * b3.w;

__global__ __launch_bounds__(256) void dist_argmin_kernel(
    const float* __restrict__ z, const float* __restrict__ emb,
    const float2* __restrict__ eepair, const float* __restrict__ zinv,
    int ne, int* __restrict__ idxw, float* __restrict__ counts,
    float* __restrict__ out_idx) {
  __shared__ float As[TM][BK + 4];   // +4 pad keeps 16B align, breaks bank alias
  __shared__ float Bs[BK][TN];       // transposed store: [k][code]
  __shared__ float Sb[TM][33];
  __shared__ int   Si[TM][33];

  const int tid = threadIdx.x;
  const int tx = tid & 31;
  const int ty = tid >> 5;
  const int m0 = blockIdx.x * TM;

  float zr[4];
#pragma unroll
  for (int i = 0; i < 4; ++i) zr[i] = zinv[m0 + ty * 4 + i];

  float best[4] = {FLT_MAX, FLT_MAX, FLT_MAX, FLT_MAX};
  int bidx[4] = {0, 0, 0, 0};

  const int a_row = tid >> 3;
  const int a_kg = (tid & 7) << 2;
  const int b_code = tid >> 1;
  const int b_kh = (tid & 1) << 4;

  for (int n0 = 0; n0 < ne; n0 += TN) {
    float acc[4][4] = {{0.f, 0.f, 0.f, 0.f}, {0.f, 0.f, 0.f, 0.f},
                       {0.f, 0.f, 0.f, 0.f}, {0.f, 0.f, 0.f, 0.f}};
    for (int k0 = 0; k0 < DIM; k0 += BK) {
      // stage z tile (coalesced float4)
      *(float4*)&As[a_row][a_kg] =
          *(const float4*)&z[(size_t)(m0 + a_row) * DIM + k0 + a_kg];
      // stage emb tile, transposed into Bs[k][code]
      const float* src = &emb[(size_t)(n0 + b_code) * DIM + k0 + b_kh];
#pragma unroll
      for (int i = 0; i < 4; ++i) {
        float4 v = *(const float4*)(src + i * 4);
        Bs[b_kh + i * 4 + 0][b_code] = v.x;
        Bs[b_kh + i * 4 + 1][b_code] = v.y;
        Bs[b_kh + i * 4 + 2][b_code] = v.z;
        Bs[b_kh + i * 4 + 3][b_code] = v.w;
      }
      __syncthreads();
#pragma unroll
      for (int kk = 0; kk < BK; kk += 4) {
        float4 a0 = *(const float4*)&As[ty * 4 + 0][kk];
        float4 a1 = *(const float4*)&As[ty * 4 + 1][kk];
        float4 a2 = *(const float4*)&As[ty * 4 + 2][kk];
        float4 a3 = *(const float4*)&As[ty * 4 + 3][kk];
        float4 b0 = *(const float4*)&Bs[kk + 0][tx * 4];
        float4 b1 = *(const float4*)&Bs[kk + 1][tx * 4];
        float4 b2 = *(const float4*)&Bs[kk + 2][tx * 4];
        float4 b3 = *(const float4*)&Bs[kk + 3][tx * 4];
        ROWFMA(a0, 0)
        ROWFMA(a1, 1)
        ROWFMA(a2, 2)
        ROWFMA(a3, 3)
      }
      __syncthreads();
    }
    // epilogue: score = ee_j - 2*zinv_r*einv_j*dot(z_raw, emb_raw)
#pragma unroll
    for (int c = 0; c < 4; ++c) {
      int j = n0 + tx * 4 + c;
      float2 ep = eepair[j];
      float w = 2.0f * ep.y;
#pragma unroll
      for (int i = 0; i < 4; ++i) {
        float s = ep.x - w * zr[i] * acc[i][c];
        if (s < best[i]) { best[i] = s; bidx[i] = j; }  // strict < keeps first
      }
    }
  }

  // reduce best across the 32 tx columns per row
#pragma unroll
  for (int i = 0; i < 4; ++i) {
    Sb[ty * 4 + i][tx] = best[i];
    Si[ty * 4 + i][tx] = bidx[i];
  }
  __syncthreads();
  if (tid < TM) {
    float bs = Sb[tid][0];
    int bj = Si[tid][0];
    for (int t = 1; t < 32; ++t) {
      float s = Sb[tid][t];
      int jj = Si[tid][t];
      if (s < bs || (s == bs && jj < bj)) { bs = s; bj = jj; }
    }
    idxw[m0 + tid] = bj;
    out_idx[m0 + tid] = (float)bj;   // harness reads whole out buf as fp32
    atomicAdd(&counts[bj], 1.0f);
  }
}

// one wave per row: z_q_st = normalize(z + (q - z)); loss partial on
// (normalize(q) - z*zinv)^2
__global__ __launch_bounds__(256) void finalize_rows_kernel(
    const float* __restrict__ z, const float* __restrict__ emb,
    const int* __restrict__ idxw, const float* __restrict__ zinv,
    float* __restrict__ out_zq, float* __restrict__ lossacc) {
  int row = blockIdx.x * 4 + (threadIdx.x >> 6);
  int lane = threadIdx.x & 63;
  int j = idxw[row];
  const float* zp = z + (size_t)row * DIM;
  const float* qp = emb + (size_t)j * DIM;
  float zl[8], ql[8], tl[8];
  float st = 0.f, sq = 0.f;
#pragma unroll
  for (int i = 0; i < 8; ++i) {
    int k = i * 64 + lane;
    float zv = zp[k], qv = qp[k];
    float t = zv + (qv - zv);  // straight-through, literal arithmetic
    zl[i] = zv; ql[i] = qv; tl[i] = t;
    st += t * t;
    sq += qv * qv;
  }
  st = wave_sum(st);
  sq = wave_sum(sq);
  float dt = fmaxf(sqrtf(st), EPSN);
  float dq = fmaxf(sqrtf(sq), EPSN);
  float zi = zinv[row];
  float lp = 0.f;
#pragma unroll
  for (int i = 0; i < 8; ++i) {
    int k = i * 64 + lane;
    out_zq[(size_t)row * DIM + k] = tl[i] / dt;
    float e = ql[i] / dq - zl[i] * zi;
    lp += e * e;
  }
  lp = wave_sum(lp);
  if (lane == 0) atomicAdd(lossacc, lp);
}

// single block: loss scalar + perplexity from counts
__global__ __launch_bounds__(256) void scalars_kernel(
    const float* __restrict__ counts, const float* __restrict__ lossacc,
    int ne, float inv_n, float inv_total, float* __restrict__ out_loss,
    float* __restrict__ out_perp) {
  __shared__ float red[4];
  int tid = threadIdx.x;
  float s = 0.f;
  for (int jj = tid; jj < ne; jj += 256) {
    float p = counts[jj] * inv_n;
    s += p * logf(p + 1e-10f);
  }
  s = wave_sum(s);
  if ((tid & 63) == 0) red[tid >> 6] = s;
  __syncthreads();
  if (tid == 0) {
    float t = red[0] + red[1] + red[2] + red[3];
    *out_perp = expf(-t);
    *out_loss = 1.25f * lossacc[0] * inv_total;  // (1+BETA)*mean, sg() is identity fwd
  }
}

extern "C" void kernel_launch(void* const* d_in, const int* in_sizes, int n_in,
                              void* d_out, int out_size, void* d_ws, size_t ws_size,
                              hipStream_t stream) {
  const float* z = (const float*)d_in[0];
  const float* emb = (const float*)d_in[1];
  float* out = (float*)d_out;
  float* ws = (float*)d_ws;

  const int nrows = in_sizes[0] / DIM;  // 32768
  const int ne = in_sizes[1] / DIM;     // 8192

  // workspace layout (floats)
  float2* eepair = (float2*)ws;                 // ne float2
  float* zinv = ws + 2 * ne;                    // nrows
  int* idxw = (int*)(ws + 2 * ne + nrows);      // nrows
  float* counts = ws + 2 * ne + 2 * nrows;      // ne
  float* lossacc = counts + ne;                 // 1

  float* out_zq = out + 1;
  float* out_idx = out + 1 + (size_t)nrows * DIM;
  float* out_perp = out + (size_t)out_size - 1;

  hipMemsetAsync(counts, 0, (ne + 1) * sizeof(float), stream);
  emb_norm_kernel<<<ne / 4, 256, 0, stream>>>(emb, eepair);
  z_norm_kernel<<<nrows / 4, 256, 0, stream>>>(z, zinv);
  dist_argmin_kernel<<<nrows / TM, 256, 0, stream>>>(z, emb, eepair, zinv, ne,
                                                     idxw, counts, out_idx);
  finalize_rows_kernel<<<nrows / 4, 256, 0, stream>>>(z, emb, idxw, zinv,
                                                      out_zq, lossacc);
  scalars_kernel<<<1, 256, 0, stream>>>(counts, lossacc, ne,
                                        1.0f / (float)nrows,
                                        1.0f / (float)((size_t)nrows * DIM),
                                        out, out_perp);
}

// Round 2
// 1668.970 us; speedup vs baseline: 3.7137x; 3.7137x over previous
//
#include <hip/hip_runtime.h>
#include <float.h>
#include <math.h>

#define DIM 512
#define EPSN 1e-12f

typedef _Float16 f16x8 __attribute__((ext_vector_type(8)));
typedef float f32x4 __attribute__((ext_vector_type(4)));

// ---------------- wave (64-lane) sum ----------------
__device__ inline float wave_sum(float v) {
#pragma unroll
  for (int o = 32; o > 0; o >>= 1) v += __shfl_xor(v, o, 64);
  return v;
}

// one wave per emb row: eepair[j] = { sum(embn^2), 1/max(||emb_j||,eps) }
__global__ __launch_bounds__(256) void emb_norm_kernel(
    const float* __restrict__ emb, float2* __restrict__ eepair) {
  int row = blockIdx.x * 4 + (threadIdx.x >> 6);
  int lane = threadIdx.x & 63;
  const float* p = emb + (size_t)row * DIM;
  float x[8];
  float ss = 0.f;
#pragma unroll
  for (int i = 0; i < 8; ++i) { x[i] = p[i * 64 + lane]; ss += x[i] * x[i]; }
  ss = wave_sum(ss);
  float d = fmaxf(sqrtf(ss), EPSN);
  float ee = 0.f;
#pragma unroll
  for (int i = 0; i < 8; ++i) { float y = x[i] / d; ee += y * y; }
  ee = wave_sum(ee);
  if (lane == 0) eepair[row] = make_float2(ee, 1.0f / d);
}

// one wave per z row: zinv[n] = 1/max(||z_n||,eps)
__global__ __launch_bounds__(256) void z_norm_kernel(
    const float* __restrict__ z, float* __restrict__ zinv) {
  int row = blockIdx.x * 4 + (threadIdx.x >> 6);
  int lane = threadIdx.x & 63;
  const float* p = z + (size_t)row * DIM;
  float ss = 0.f;
#pragma unroll
  for (int i = 0; i < 8; ++i) { float v = p[i * 64 + lane]; ss += v * v; }
  ss = wave_sum(ss);
  if (lane == 0) zinv[row] = 1.0f / fmaxf(sqrtf(ss), EPSN);
}

// ---------------- MFMA distance + argmin ----------------
// 512 blocks x 256 threads (4 waves). Each wave owns 16 rows; A (z) hi/lo fp16
// fragments for full K=512 persistent in regs (128 VGPR). B (emb) tile =
// 16 codes x 512, fp32->fp16 hi/lo converted during staging into
// double-buffered LDS. 3 MFMAs/chunk (hh, lh, hl) ~= fp32-accurate dot.
// C/D layout: col=lane&15, row=quad*4+reg  (m89); A: A[m=lane&15][k=quad*8+j].
#define NE_TILE 16
#define BSTRIDE 520  // 512 + 8 f16 pad -> 260 dwords = 4 mod 32: 2-way banks (free)

__global__ __launch_bounds__(256, 2) void dist_argmin_kernel(
    const float* __restrict__ z, const float* __restrict__ emb,
    const float2* __restrict__ eepair, const float* __restrict__ zinv,
    int ne, int* __restrict__ idxw, float* __restrict__ counts,
    float* __restrict__ out_idx) {
  __shared__ _Float16 Bh[2][NE_TILE][BSTRIDE];
  __shared__ _Float16 Bl[2][NE_TILE][BSTRIDE];

  const int tid = threadIdx.x;
  const int wave = tid >> 6;
  const int lane = tid & 63;
  const int col = lane & 15;
  const int quad = lane >> 4;
  const int m0 = blockIdx.x * 64;
  const int arow = m0 + wave * 16 + col;

  // persistent A fragments (hi/lo), 16 k-chunks of 32
  f16x8 Ah[16], Al[16];
  {
    const float* zp = z + (size_t)arow * DIM + quad * 8;
#pragma unroll
    for (int kc = 0; kc < 16; ++kc) {
      float4 a = *(const float4*)(zp + kc * 32);
      float4 b = *(const float4*)(zp + kc * 32 + 4);
      float v[8] = {a.x, a.y, a.z, a.w, b.x, b.y, b.z, b.w};
#pragma unroll
      for (int k = 0; k < 8; ++k) {
        _Float16 h = (_Float16)v[k];
        Ah[kc][k] = h;
        Al[kc][k] = (_Float16)(v[k] - (float)h);
      }
    }
  }

  float zr[4];
#pragma unroll
  for (int i = 0; i < 4; ++i) zr[i] = zinv[m0 + wave * 16 + quad * 4 + i];

  // staging: thread covers code sc, elements so..so+31
  const int sc = tid >> 4;
  const int so = (tid & 15) * 32;
  float4 st[8];

  float best[4] = {FLT_MAX, FLT_MAX, FLT_MAX, FLT_MAX};
  int bidx[4] = {0, 0, 0, 0};

  // prefetch + write tile 0
  {
    const float* src = emb + (size_t)sc * DIM + so;
#pragma unroll
    for (int j = 0; j < 8; ++j) st[j] = *(const float4*)(src + j * 4);
#pragma unroll
    for (int jj = 0; jj < 4; ++jj) {
      float4 a = st[2 * jj], b = st[2 * jj + 1];
      float v[8] = {a.x, a.y, a.z, a.w, b.x, b.y, b.z, b.w};
      f16x8 h, l;
#pragma unroll
      for (int k = 0; k < 8; ++k) {
        _Float16 hh = (_Float16)v[k];
        h[k] = hh;
        l[k] = (_Float16)(v[k] - (float)hh);
      }
      *(f16x8*)&Bh[0][sc][so + jj * 8] = h;
      *(f16x8*)&Bl[0][sc][so + jj * 8] = l;
    }
  }
  __syncthreads();

  const int ntiles = ne / NE_TILE;
  for (int t = 0; t < ntiles; ++t) {
    const int buf = t & 1;
    const int n0 = t * NE_TILE;

    // issue next tile's global loads (in flight across the MFMA loop)
    if (t + 1 < ntiles) {
      const float* src = emb + (size_t)(n0 + NE_TILE + sc) * DIM + so;
#pragma unroll
      for (int j = 0; j < 8; ++j) st[j] = *(const float4*)(src + j * 4);
    }
    float2 ep = eepair[n0 + col];

    f32x4 acc[4] = {{0.f, 0.f, 0.f, 0.f}, {0.f, 0.f, 0.f, 0.f},
                    {0.f, 0.f, 0.f, 0.f}, {0.f, 0.f, 0.f, 0.f}};
    const _Float16* bhp = &Bh[buf][col][quad * 8];
    const _Float16* blp = &Bl[buf][col][quad * 8];
#pragma unroll
    for (int kc = 0; kc < 16; ++kc) {
      f16x8 bh = *(const f16x8*)(bhp + kc * 32);
      f16x8 bl = *(const f16x8*)(blp + kc * 32);
      acc[kc & 3] =
          __builtin_amdgcn_mfma_f32_16x16x32_f16(Ah[kc], bh, acc[kc & 3], 0, 0, 0);
      acc[(kc + 1) & 3] =
          __builtin_amdgcn_mfma_f32_16x16x32_f16(Al[kc], bh, acc[(kc + 1) & 3], 0, 0, 0);
      acc[(kc + 2) & 3] =
          __builtin_amdgcn_mfma_f32_16x16x32_f16(Ah[kc], bl, acc[(kc + 2) & 3], 0, 0, 0);
    }

    // convert + write next tile into the other buffer (waits on vmcnt here)
    if (t + 1 < ntiles) {
      const int ob = buf ^ 1;
#pragma unroll
      for (int jj = 0; jj < 4; ++jj) {
        float4 a = st[2 * jj], b = st[2 * jj + 1];
        float v[8] = {a.x, a.y, a.z, a.w, b.x, b.y, b.z, b.w};
        f16x8 h, l;
#pragma unroll
        for (int k = 0; k < 8; ++k) {
          _Float16 hh = (_Float16)v[k];
          h[k] = hh;
          l[k] = (_Float16)(v[k] - (float)hh);
        }
        *(f16x8*)&Bh[ob][sc][so + jj * 8] = h;
        *(f16x8*)&Bl[ob][sc][so + jj * 8] = l;
      }
    }

    // epilogue: score = ee_j - 2*einv_j*zinv_r*dot
    float w2 = 2.0f * ep.y;
    int j = n0 + col;
#pragma unroll
    for (int i = 0; i < 4; ++i) {
      float d = acc[0][i] + acc[1][i] + acc[2][i] + acc[3][i];
      float s = ep.x - w2 * zr[i] * d;
      if (s < best[i]) { best[i] = s; bidx[i] = j; }  // strict < -> first occurrence
    }
    __syncthreads();
  }

  // merge across the 16 columns within each quad (xor 1,2,4,8 stays in quad)
#pragma unroll
  for (int i = 0; i < 4; ++i) {
    float bs = best[i];
    int bj = bidx[i];
#pragma unroll
    for (int off = 1; off < 16; off <<= 1) {
      float os = __shfl_xor(bs, off, 64);
      int oi = __shfl_xor(bj, off, 64);
      if (os < bs || (os == bs && oi < bj)) { bs = os; bj = oi; }
    }
    if (col == 0) {
      int row = m0 + wave * 16 + quad * 4 + i;
      idxw[row] = bj;
      out_idx[row] = (float)bj;
      atomicAdd(&counts[bj], 1.0f);
    }
  }
}

// one wave per row: z_q_st = normalize(q); loss partial on
// (normalize(q) - z*zinv)^2
__global__ __launch_bounds__(256) void finalize_rows_kernel(
    const float* __restrict__ z, const float* __restrict__ emb,
    const int* __restrict__ idxw, const float* __restrict__ zinv,
    float* __restrict__ out_zq, float* __restrict__ lossacc) {
  int row = blockIdx.x * 4 + (threadIdx.x >> 6);
  int lane = threadIdx.x & 63;
  int j = idxw[row];
  const float* zp = z + (size_t)row * DIM;
  const float* qp = emb + (size_t)j * DIM;
  float zl[8], ql[8], tl[8];
  float st = 0.f, sq = 0.f;
#pragma unroll
  for (int i = 0; i < 8; ++i) {
    int k = i * 64 + lane;
    float zv = zp[k], qv = qp[k];
    float t = zv + (qv - zv);  // straight-through, literal arithmetic
    zl[i] = zv; ql[i] = qv; tl[i] = t;
    st += t * t;
    sq += qv * qv;
  }
  st = wave_sum(st);
  sq = wave_sum(sq);
  float dt = fmaxf(sqrtf(st), EPSN);
  float dq = fmaxf(sqrtf(sq), EPSN);
  float zi = zinv[row];
  float lp = 0.f;
#pragma unroll
  for (int i = 0; i < 8; ++i) {
    int k = i * 64 + lane;
    out_zq[(size_t)row * DIM + k] = tl[i] / dt;
    float e = ql[i] / dq - zl[i] * zi;
    lp += e * e;
  }
  lp = wave_sum(lp);
  if (lane == 0) atomicAdd(lossacc, lp);
}

// single block: loss scalar + perplexity from counts
__global__ __launch_bounds__(256) void scalars_kernel(
    const float* __restrict__ counts, const float* __restrict__ lossacc,
    int ne, float inv_n, float inv_total, float* __restrict__ out_loss,
    float* __restrict__ out_perp) {
  __shared__ float red[4];
  int tid = threadIdx.x;
  float s = 0.f;
  for (int jj = tid; jj < ne; jj += 256) {
    float p = counts[jj] * inv_n;
    s += p * logf(p + 1e-10f);
  }
  s = wave_sum(s);
  if ((tid & 63) == 0) red[tid >> 6] = s;
  __syncthreads();
  if (tid == 0) {
    float t = red[0] + red[1] + red[2] + red[3];
    *out_perp = expf(-t);
    *out_loss = 1.25f * lossacc[0] * inv_total;  // (1+BETA)*mean, sg() identity fwd
  }
}

extern "C" void kernel_launch(void* const* d_in, const int* in_sizes, int n_in,
                              void* d_out, int out_size, void* d_ws, size_t ws_size,
                              hipStream_t stream) {
  const float* z = (const float*)d_in[0];
  const float* emb = (const float*)d_in[1];
  float* out = (float*)d_out;
  float* ws = (float*)d_ws;

  const int nrows = in_sizes[0] / DIM;  // 32768
  const int ne = in_sizes[1] / DIM;     // 8192

  // workspace layout (floats)
  float2* eepair = (float2*)ws;                 // ne float2
  float* zinv = ws + 2 * ne;                    // nrows
  int* idxw = (int*)(ws + 2 * ne + nrows);      // nrows
  float* counts = ws + 2 * ne + 2 * nrows;      // ne
  float* lossacc = counts + ne;                 // 1

  float* out_zq = out + 1;
  float* out_idx = out + 1 + (size_t)nrows * DIM;
  float* out_perp = out + (size_t)out_size - 1;

  hipMemsetAsync(counts, 0, (ne + 1) * sizeof(float), stream);
  emb_norm_kernel<<<ne / 4, 256, 0, stream>>>(emb, eepair);
  z_norm_kernel<<<nrows / 4, 256, 0, stream>>>(z, zinv);
  dist_argmin_kernel<<<nrows / 64, 256, 0, stream>>>(z, emb, eepair, zinv, ne,
                                                     idxw, counts, out_idx);
  finalize_rows_kernel<<<nrows / 4, 256, 0, stream>>>(z, emb, idxw, zinv,
                                                      out_zq, lossacc);
  scalars_kernel<<<1, 256, 0, stream>>>(counts, lossacc, ne,
                                        1.0f / (float)nrows,
                                        1.0f / (float)((size_t)nrows * DIM),
                                        out, out_perp);
}

// Round 3
// 1260.971 us; speedup vs baseline: 4.9153x; 1.3236x over previous
//
#include <hip/hip_runtime.h>
#include <float.h>
#include <math.h>

#define DIM 512
#define EPSN 1e-12f

typedef _Float16 f16x8 __attribute__((ext_vector_type(8)));
typedef float f32x4 __attribute__((ext_vector_type(4)));

// ---------------- wave (64-lane) sum ----------------
__device__ inline float wave_sum(float v) {
#pragma unroll
  for (int o = 32; o > 0; o >>= 1) v += __shfl_xor(v, o, 64);
  return v;
}

// one wave per emb row: eepair[j] = { sum(embn^2), 1/max(||emb_j||,eps) }
__global__ __launch_bounds__(256) void emb_norm_kernel(
    const float* __restrict__ emb, float2* __restrict__ eepair) {
  int row = blockIdx.x * 4 + (threadIdx.x >> 6);
  int lane = threadIdx.x & 63;
  const float* p = emb + (size_t)row * DIM;
  float x[8];
  float ss = 0.f;
#pragma unroll
  for (int i = 0; i < 8; ++i) { x[i] = p[i * 64 + lane]; ss += x[i] * x[i]; }
  ss = wave_sum(ss);
  float d = fmaxf(sqrtf(ss), EPSN);
  float ee = 0.f;
#pragma unroll
  for (int i = 0; i < 8; ++i) { float y = x[i] / d; ee += y * y; }
  ee = wave_sum(ee);
  if (lane == 0) eepair[row] = make_float2(ee, 1.0f / d);
}

// one wave per z row: zinv[n] = 1/max(||z_n||,eps)
__global__ __launch_bounds__(256) void z_norm_kernel(
    const float* __restrict__ z, float* __restrict__ zinv) {
  int row = blockIdx.x * 4 + (threadIdx.x >> 6);
  int lane = threadIdx.x & 63;
  const float* p = z + (size_t)row * DIM;
  float ss = 0.f;
#pragma unroll
  for (int i = 0; i < 8; ++i) { float v = p[i * 64 + lane]; ss += v * v; }
  ss = wave_sum(ss);
  if (lane == 0) zinv[row] = 1.0f / fmaxf(sqrtf(ss), EPSN);
}

// ---------------- MFMA distance + argmin ----------------
// 256 blocks x 256 threads (4 waves, 1 wave/SIMD). Each wave owns 32 rows as
// TWO 16-row MFMA blocks with persistent hi/lo fp16 A fragments (256 VGPR) --
// each B fragment pair (bh,bl) feeds 6 MFMAs, making the kernel MFMA-bound
// instead of LDS-read-bound. B staged hi/lo into double-buffered LDS with an
// XOR chunk swizzle that makes BOTH the write pattern (q fast, c const) and
// the read pattern (c fast, q slow) conflict-free:
//   phys_q = q ^ (c&7) ^ ((q>>2)&7)     (q = 16B chunk index 0..63)
#define NE_TILE 16

#define MFMA16(A, B, C) __builtin_amdgcn_mfma_f32_16x16x32_f16(A, B, C, 0, 0, 0)

__global__ __launch_bounds__(256, 1) void dist_argmin_kernel(
    const float* __restrict__ z, const float* __restrict__ emb,
    const float2* __restrict__ eepair, const float* __restrict__ zinv,
    int ne, int* __restrict__ idxw, float* __restrict__ counts,
    float* __restrict__ out_idx) {
  __shared__ _Float16 Bh[2][NE_TILE][512];
  __shared__ _Float16 Bl[2][NE_TILE][512];

  const int tid = threadIdx.x;
  const int wave = tid >> 6;
  const int lane = tid & 63;
  const int col = lane & 15;
  const int quad = lane >> 4;
  const int m0 = blockIdx.x * 128;
  const int r0 = m0 + wave * 32;

  // persistent A fragments (hi/lo) for two 16-row blocks: 64 x f16x8 = 256 VGPR
  f16x8 Ah[2][16], Al[2][16];
#pragma unroll
  for (int rb = 0; rb < 2; ++rb) {
    const float* zp = z + (size_t)(r0 + rb * 16 + col) * DIM + quad * 8;
#pragma unroll
    for (int kc = 0; kc < 16; ++kc) {
      float4 a = *(const float4*)(zp + kc * 32);
      float4 b = *(const float4*)(zp + kc * 32 + 4);
      float v[8] = {a.x, a.y, a.z, a.w, b.x, b.y, b.z, b.w};
#pragma unroll
      for (int k = 0; k < 8; ++k) {
        _Float16 h = (_Float16)v[k];
        Ah[rb][kc][k] = h;
        Al[rb][kc][k] = (_Float16)(v[k] - (float)h);
      }
    }
  }

  float zr[2][4];
#pragma unroll
  for (int rb = 0; rb < 2; ++rb)
#pragma unroll
    for (int i = 0; i < 4; ++i)
      zr[rb][i] = zinv[r0 + rb * 16 + quad * 4 + i];

  float best[2][4] = {{FLT_MAX, FLT_MAX, FLT_MAX, FLT_MAX},
                      {FLT_MAX, FLT_MAX, FLT_MAX, FLT_MAX}};
  int bidx[2][4] = {{0, 0, 0, 0}, {0, 0, 0, 0}};

  // staging: thread covers code sc (global-coalesced 128B per thread)
  const int sc = tid >> 4;
  const int t15 = tid & 15;
  float4 st[8];

  // prefetch + swizzled write of tile 0
  {
    const float* src = emb + (size_t)sc * DIM + t15 * 32;
#pragma unroll
    for (int j = 0; j < 8; ++j) st[j] = *(const float4*)(src + j * 4);
#pragma unroll
    for (int jj = 0; jj < 4; ++jj) {
      float4 a = st[2 * jj], b = st[2 * jj + 1];
      float v[8] = {a.x, a.y, a.z, a.w, b.x, b.y, b.z, b.w};
      f16x8 h, l;
#pragma unroll
      for (int k = 0; k < 8; ++k) {
        _Float16 hh = (_Float16)v[k];
        h[k] = hh;
        l[k] = (_Float16)(v[k] - (float)hh);
      }
      int q = t15 * 4 + jj;
      int p = q ^ (sc & 7) ^ (t15 & 7);
      *(f16x8*)&Bh[0][sc][p * 8] = h;
      *(f16x8*)&Bl[0][sc][p * 8] = l;
    }
  }
  __syncthreads();

  const int ntiles = ne / NE_TILE;
  for (int t = 0; t < ntiles; ++t) {
    const int buf = t & 1;
    const int n0 = t * NE_TILE;

    // issue next tile's global loads (in flight across the MFMA loop)
    if (t + 1 < ntiles) {
      const float* src = emb + (size_t)(n0 + NE_TILE + sc) * DIM + t15 * 32;
#pragma unroll
      for (int j = 0; j < 8; ++j) st[j] = *(const float4*)(src + j * 4);
    }
    float2 ep = eepair[n0 + col];

    f32x4 acc[2][3];
#pragma unroll
    for (int rb = 0; rb < 2; ++rb)
#pragma unroll
      for (int a = 0; a < 3; ++a) acc[rb][a] = (f32x4){0.f, 0.f, 0.f, 0.f};

#pragma unroll
    for (int kc = 0; kc < 16; ++kc) {
      int q = quad + 4 * kc;
      int p = q ^ (col & 7) ^ (kc & 7);
      f16x8 bh = *(const f16x8*)&Bh[buf][col][p * 8];
      f16x8 bl = *(const f16x8*)&Bl[buf][col][p * 8];
      acc[0][0] = MFMA16(Ah[0][kc], bh, acc[0][0]);
      acc[1][0] = MFMA16(Ah[1][kc], bh, acc[1][0]);
      acc[0][1] = MFMA16(Al[0][kc], bh, acc[0][1]);
      acc[1][1] = MFMA16(Al[1][kc], bh, acc[1][1]);
      acc[0][2] = MFMA16(Ah[0][kc], bl, acc[0][2]);
      acc[1][2] = MFMA16(Ah[1][kc], bl, acc[1][2]);
    }

    // convert + swizzled write of next tile into the other buffer
    if (t + 1 < ntiles) {
      const int ob = buf ^ 1;
#pragma unroll
      for (int jj = 0; jj < 4; ++jj) {
        float4 a = st[2 * jj], b = st[2 * jj + 1];
        float v[8] = {a.x, a.y, a.z, a.w, b.x, b.y, b.z, b.w};
        f16x8 h, l;
#pragma unroll
        for (int k = 0; k < 8; ++k) {
          _Float16 hh = (_Float16)v[k];
          h[k] = hh;
          l[k] = (_Float16)(v[k] - (float)hh);
        }
        int q = t15 * 4 + jj;
        int p = q ^ (sc & 7) ^ (t15 & 7);
        *(f16x8*)&Bh[ob][sc][p * 8] = h;
        *(f16x8*)&Bl[ob][sc][p * 8] = l;
      }
    }

    // epilogue: score = ee_j - 2*einv_j*zinv_r*dot
    float w2 = 2.0f * ep.y;
    int j = n0 + col;
#pragma unroll
    for (int rb = 0; rb < 2; ++rb)
#pragma unroll
      for (int i = 0; i < 4; ++i) {
        float d = acc[rb][0][i] + acc[rb][1][i] + acc[rb][2][i];
        float s = ep.x - w2 * zr[rb][i] * d;
        if (s < best[rb][i]) { best[rb][i] = s; bidx[rb][i] = j; }
      }
    __syncthreads();
  }

  // merge across the 16 columns within each quad (xor 1,2,4,8 stays in quad)
#pragma unroll
  for (int rb = 0; rb < 2; ++rb)
#pragma unroll
    for (int i = 0; i < 4; ++i) {
      float bs = best[rb][i];
      int bj = bidx[rb][i];
#pragma unroll
      for (int off = 1; off < 16; off <<= 1) {
        float os = __shfl_xor(bs, off, 64);
        int oi = __shfl_xor(bj, off, 64);
        if (os < bs || (os == bs && oi < bj)) { bs = os; bj = oi; }
      }
      if (col == 0) {
        int row = r0 + rb * 16 + quad * 4 + i;
        idxw[row] = bj;
        out_idx[row] = (float)bj;
        atomicAdd(&counts[bj], 1.0f);
      }
    }
}

// one wave per row: z_q_st = normalize(q); per-block loss partial (no global
// same-address atomics -- they serialized at one L2 bank)
__global__ __launch_bounds__(256) void finalize_rows_kernel(
    const float* __restrict__ z, const float* __restrict__ emb,
    const int* __restrict__ idxw, const float* __restrict__ zinv,
    float* __restrict__ out_zq, float* __restrict__ lpart) {
  __shared__ float red[4];
  int row = blockIdx.x * 4 + (threadIdx.x >> 6);
  int lane = threadIdx.x & 63;
  int j = idxw[row];
  const float* zp = z + (size_t)row * DIM;
  const float* qp = emb + (size_t)j * DIM;
  float zl[8], ql[8], tl[8];
  float st = 0.f, sq = 0.f;
#pragma unroll
  for (int i = 0; i < 8; ++i) {
    int k = i * 64 + lane;
    float zv = zp[k], qv = qp[k];
    float t = zv + (qv - zv);  // straight-through, literal arithmetic
    zl[i] = zv; ql[i] = qv; tl[i] = t;
    st += t * t;
    sq += qv * qv;
  }
  st = wave_sum(st);
  sq = wave_sum(sq);
  float dt = fmaxf(sqrtf(st), EPSN);
  float dq = fmaxf(sqrtf(sq), EPSN);
  float zi = zinv[row];
  float lp = 0.f;
#pragma unroll
  for (int i = 0; i < 8; ++i) {
    int k = i * 64 + lane;
    out_zq[(size_t)row * DIM + k] = tl[i] / dt;
    float e = ql[i] / dq - zl[i] * zi;
    lp += e * e;
  }
  lp = wave_sum(lp);
  if (lane == 0) red[threadIdx.x >> 6] = lp;
  __syncthreads();
  if (threadIdx.x == 0) lpart[blockIdx.x] = red[0] + red[1] + red[2] + red[3];
}

// single block: loss scalar (sum of block partials) + perplexity from counts
__global__ __launch_bounds__(256) void scalars_kernel(
    const float* __restrict__ counts, const float* __restrict__ lpart,
    int ne, int nblk, float inv_n, float inv_total,
    float* __restrict__ out_loss, float* __restrict__ out_perp) {
  __shared__ float red[8];
  int tid = threadIdx.x;
  float s = 0.f;
  for (int jj = tid; jj < ne; jj += 256) {
    float p = counts[jj] * inv_n;
    s += p * logf(p + 1e-10f);
  }
  float l = 0.f;
  for (int jj = tid; jj < nblk; jj += 256) l += lpart[jj];
  s = wave_sum(s);
  l = wave_sum(l);
  if ((tid & 63) == 0) { red[tid >> 6] = s; red[4 + (tid >> 6)] = l; }
  __syncthreads();
  if (tid == 0) {
    float t = red[0] + red[1] + red[2] + red[3];
    float lt = red[4] + red[5] + red[6] + red[7];
    *out_perp = expf(-t);
    *out_loss = 1.25f * lt * inv_total;  // (1+BETA)*mean, sg() identity fwd
  }
}

extern "C" void kernel_launch(void* const* d_in, const int* in_sizes, int n_in,
                              void* d_out, int out_size, void* d_ws, size_t ws_size,
                              hipStream_t stream) {
  const float* z = (const float*)d_in[0];
  const float* emb = (const float*)d_in[1];
  float* out = (float*)d_out;
  float* ws = (float*)d_ws;

  const int nrows = in_sizes[0] / DIM;  // 32768
  const int ne = in_sizes[1] / DIM;     // 8192
  const int nfin = nrows / 4;           // finalize blocks

  // workspace layout (floats)
  float2* eepair = (float2*)ws;                  // ne float2
  float* zinv = ws + 2 * ne;                     // nrows
  int* idxw = (int*)(ws + 2 * ne + nrows);       // nrows
  float* counts = ws + 2 * ne + 2 * nrows;       // ne
  float* lpart = counts + ne;                    // nfin

  float* out_zq = out + 1;
  float* out_idx = out + 1 + (size_t)nrows * DIM;
  float* out_perp = out + (size_t)out_size - 1;

  hipMemsetAsync(counts, 0, ne * sizeof(float), stream);
  emb_norm_kernel<<<ne / 4, 256, 0, stream>>>(emb, eepair);
  z_norm_kernel<<<nrows / 4, 256, 0, stream>>>(z, zinv);
  dist_argmin_kernel<<<nrows / 128, 256, 0, stream>>>(z, emb, eepair, zinv, ne,
                                                      idxw, counts, out_idx);
  finalize_rows_kernel<<<nfin, 256, 0, stream>>>(z, emb, idxw, zinv,
                                                 out_zq, lpart);
  scalars_kernel<<<1, 256, 0, stream>>>(counts, lpart, ne, nfin,
                                        1.0f / (float)nrows,
                                        1.0f / (float)((size_t)nrows * DIM),
                                        out, out_perp);
}

// Round 4
// 1120.113 us; speedup vs baseline: 5.5334x; 1.1258x over previous
//
#include <hip/hip_runtime.h>
#include <float.h>
#include <math.h>

#define DIM 512
#define EPSN 1e-12f

typedef _Float16 f16x8 __attribute__((ext_vector_type(8)));
typedef float f32x4 __attribute__((ext_vector_type(4)));

// async global -> LDS, 16B per lane; lds dest = wave-uniform base + lane*16
__device__ inline void gll16(const void* g, void* l) {
  __builtin_amdgcn_global_load_lds(
      (__attribute__((address_space(1))) void*)g,
      (__attribute__((address_space(3))) void*)l, 16, 0, 0);
}

// ---------------- wave (64-lane) sum ----------------
__device__ inline float wave_sum(float v) {
#pragma unroll
  for (int o = 32; o > 0; o >>= 1) v += __shfl_xor(v, o, 64);
  return v;
}

// one wave per emb row: eepair[j] = { sum(embn^2), 1/max(||emb_j||,eps) }
__global__ __launch_bounds__(256) void emb_norm_kernel(
    const float* __restrict__ emb, float2* __restrict__ eepair) {
  int row = blockIdx.x * 4 + (threadIdx.x >> 6);
  int lane = threadIdx.x & 63;
  const float* p = emb + (size_t)row * DIM;
  float x[8];
  float ss = 0.f;
#pragma unroll
  for (int i = 0; i < 8; ++i) { x[i] = p[i * 64 + lane]; ss += x[i] * x[i]; }
  ss = wave_sum(ss);
  float d = fmaxf(sqrtf(ss), EPSN);
  float ee = 0.f;
#pragma unroll
  for (int i = 0; i < 8; ++i) { float y = x[i] / d; ee += y * y; }
  ee = wave_sum(ee);
  if (lane == 0) eepair[row] = make_float2(ee, 1.0f / d);
}

// one wave per z row: zinv[n] = 1/max(||z_n||,eps)
__global__ __launch_bounds__(256) void z_norm_kernel(
    const float* __restrict__ z, float* __restrict__ zinv) {
  int row = blockIdx.x * 4 + (threadIdx.x >> 6);
  int lane = threadIdx.x & 63;
  const float* p = z + (size_t)row * DIM;
  float ss = 0.f;
#pragma unroll
  for (int i = 0; i < 8; ++i) { float v = p[i * 64 + lane]; ss += v * v; }
  ss = wave_sum(ss);
  if (lane == 0) zinv[row] = 1.0f / fmaxf(sqrtf(ss), EPSN);
}

// ---------------- emb -> swizzled hi/lo fp16 (LDS tile order) ----------------
// swz layout: chunk c = (tile16 * 16 + kc) * 2 + half, each chunk = 64 lanes
// x 8 f16 (1 KB); element (lane = quad*16+col, j) = emb[tile16*16+col]
// [kc*32 + quad*8 + j], split hi/lo. This IS the MFMA B-fragment order, so
// dist staging is a plain linear async copy and all LDS traffic is
// contiguous-per-lane (conflict-free).
__global__ __launch_bounds__(256) void emb_split_kernel(
    const float* __restrict__ emb, _Float16* __restrict__ swz) {
  int g = blockIdx.x * 256 + threadIdx.x;  // = t*1024 + kc*64 + lane
  int lane = g & 63;
  int kc = (g >> 6) & 15;
  int t = g >> 10;
  int code = t * 16 + (lane & 15);
  int k0 = kc * 32 + (lane >> 4) * 8;
  const float* src = emb + (size_t)code * DIM + k0;
  float4 a = *(const float4*)src;
  float4 b = *(const float4*)(src + 4);
  float v[8] = {a.x, a.y, a.z, a.w, b.x, b.y, b.z, b.w};
  f16x8 h, l;
#pragma unroll
  for (int k = 0; k < 8; ++k) {
    _Float16 hh = (_Float16)v[k];
    h[k] = hh;
    l[k] = (_Float16)(v[k] - (float)hh);
  }
  size_t cbase = ((size_t)(t * 16 + kc) * 2) * 512;  // f16 units
  *(f16x8*)&swz[cbase + lane * 8] = h;
  *(f16x8*)&swz[cbase + 512 + lane * 8] = l;
}

// ---------------- MFMA distance + argmin ----------------
// 256 blocks x 256 threads (4 waves, 1 wave/SIMD). Each wave owns 32 rows as
// two 16-row MFMA blocks with persistent hi/lo fp16 A fragments; each B
// fragment pair feeds 6 MFMAs (hh, lh, hl ~= fp32-exact dot). B arrives via
// global_load_lds from the pre-swizzled array: zero staging VALU, zero
// staging VGPRs, conflict-free LDS on both sides. 32-code tiles (64 KB),
// double-buffered (128 KB LDS), prefetch issued right after the barrier.
#define MFMA16(A, B, C) __builtin_amdgcn_mfma_f32_16x16x32_f16(A, B, C, 0, 0, 0)

__global__ __launch_bounds__(256, 1) void dist_argmin_kernel(
    const float* __restrict__ z, const _Float16* __restrict__ swz,
    const float2* __restrict__ eepair, const float* __restrict__ zinv,
    int ne, int* __restrict__ idxw, float* __restrict__ counts,
    float* __restrict__ out_idx) {
  __shared__ _Float16 B[2][32768];  // 2 x 64 KB

  const int tid = threadIdx.x;
  const int wave = tid >> 6;
  const int lane = tid & 63;
  const int col = lane & 15;
  const int quad = lane >> 4;
  const int r0 = blockIdx.x * 128 + wave * 32;

  // persistent A fragments (hi/lo) for two 16-row blocks
  f16x8 Ah[2][16], Al[2][16];
#pragma unroll
  for (int rb = 0; rb < 2; ++rb) {
    const float* zp = z + (size_t)(r0 + rb * 16 + col) * DIM + quad * 8;
#pragma unroll
    for (int kc = 0; kc < 16; ++kc) {
      float4 a = *(const float4*)(zp + kc * 32);
      float4 b = *(const float4*)(zp + kc * 32 + 4);
      float v[8] = {a.x, a.y, a.z, a.w, b.x, b.y, b.z, b.w};
#pragma unroll
      for (int k = 0; k < 8; ++k) {
        _Float16 h = (_Float16)v[k];
        Ah[rb][kc][k] = h;
        Al[rb][kc][k] = (_Float16)(v[k] - (float)h);
      }
    }
  }

  float zr[2][4];
#pragma unroll
  for (int rb = 0; rb < 2; ++rb)
#pragma unroll
    for (int i = 0; i < 4; ++i)
      zr[rb][i] = zinv[r0 + rb * 16 + quad * 4 + i];

  float best[2][4] = {{FLT_MAX, FLT_MAX, FLT_MAX, FLT_MAX},
                      {FLT_MAX, FLT_MAX, FLT_MAX, FLT_MAX}};
  int bidx[2][4] = {{0, 0, 0, 0}, {0, 0, 0, 0}};

  const int ntiles = ne / 32;  // 32-code tiles; 64 chunks of 1 KB each

  // prefetch tile 0 into buf 0: wave covers chunks wave*16 .. wave*16+15
  {
    const _Float16* g0 = swz + (size_t)(wave * 16) * 512 + lane * 8;
    _Float16* l0 = &B[0][(wave * 16) * 512 + lane * 8];
#pragma unroll
    for (int i = 0; i < 16; ++i)
      gll16(g0 + i * 512, l0 + i * 512);
  }
  __syncthreads();  // vmcnt(0) drain + barrier

  for (int t = 0; t < ntiles; ++t) {
    const int buf = t & 1;

    // issue next tile's DMA immediately; MFMA loop hides its latency
    if (t + 1 < ntiles) {
      const _Float16* g0 =
          swz + ((size_t)(t + 1) * 64 + wave * 16) * 512 + lane * 8;
      _Float16* l0 = &B[buf ^ 1][(wave * 16) * 512 + lane * 8];
#pragma unroll
      for (int i = 0; i < 16; ++i)
        gll16(g0 + i * 512, l0 + i * 512);
    }

#pragma unroll
    for (int s = 0; s < 2; ++s) {
      const int n0 = (t * 2 + s) * 16;
      float2 ep = eepair[n0 + col];

      f32x4 acc[2][3];
#pragma unroll
      for (int rb = 0; rb < 2; ++rb)
#pragma unroll
        for (int a = 0; a < 3; ++a) acc[rb][a] = (f32x4){0.f, 0.f, 0.f, 0.f};

      const _Float16* bp = &B[buf][(s * 32) * 512 + lane * 8];
#pragma unroll
      for (int kc = 0; kc < 16; ++kc) {
        f16x8 bh = *(const f16x8*)(bp + (kc * 2) * 512);
        f16x8 bl = *(const f16x8*)(bp + (kc * 2 + 1) * 512);
        acc[0][0] = MFMA16(Ah[0][kc], bh, acc[0][0]);
        acc[1][0] = MFMA16(Ah[1][kc], bh, acc[1][0]);
        acc[0][1] = MFMA16(Al[0][kc], bh, acc[0][1]);
        acc[1][1] = MFMA16(Al[1][kc], bh, acc[1][1]);
        acc[0][2] = MFMA16(Ah[0][kc], bl, acc[0][2]);
        acc[1][2] = MFMA16(Ah[1][kc], bl, acc[1][2]);
      }

      // epilogue: score = ee_j - 2*einv_j*zinv_r*dot
      float w2 = 2.0f * ep.y;
      int j = n0 + col;
#pragma unroll
      for (int rb = 0; rb < 2; ++rb)
#pragma unroll
        for (int i = 0; i < 4; ++i) {
          float d = acc[rb][0][i] + acc[rb][1][i] + acc[rb][2][i];
          float sc = ep.x - w2 * zr[rb][i] * d;
          if (sc < best[rb][i]) { best[rb][i] = sc; bidx[rb][i] = j; }
        }
    }
    __syncthreads();  // drains next-tile DMA; protects buf reuse
  }

  // merge across the 16 columns within each quad (xor 1,2,4,8 stays in quad)
#pragma unroll
  for (int rb = 0; rb < 2; ++rb)
#pragma unroll
    for (int i = 0; i < 4; ++i) {
      float bs = best[rb][i];
      int bj = bidx[rb][i];
#pragma unroll
      for (int off = 1; off < 16; off <<= 1) {
        float os = __shfl_xor(bs, off, 64);
        int oi = __shfl_xor(bj, off, 64);
        if (os < bs || (os == bs && oi < bj)) { bs = os; bj = oi; }
      }
      if (col == 0) {
        int row = r0 + rb * 16 + quad * 4 + i;
        idxw[row] = bj;
        out_idx[row] = (float)bj;
        atomicAdd(&counts[bj], 1.0f);
      }
    }
}

// one wave per row: z_q_st = normalize(q); per-block loss partial
__global__ __launch_bounds__(256) void finalize_rows_kernel(
    const float* __restrict__ z, const float* __restrict__ emb,
    const int* __restrict__ idxw, const float* __restrict__ zinv,
    float* __restrict__ out_zq, float* __restrict__ lpart) {
  __shared__ float red[4];
  int row = blockIdx.x * 4 + (threadIdx.x >> 6);
  int lane = threadIdx.x & 63;
  int j = idxw[row];
  const float* zp = z + (size_t)row * DIM;
  const float* qp = emb + (size_t)j * DIM;
  float zl[8], ql[8], tl[8];
  float st = 0.f, sq = 0.f;
#pragma unroll
  for (int i = 0; i < 8; ++i) {
    int k = i * 64 + lane;
    float zv = zp[k], qv = qp[k];
    float t = zv + (qv - zv);  // straight-through, literal arithmetic
    zl[i] = zv; ql[i] = qv; tl[i] = t;
    st += t * t;
    sq += qv * qv;
  }
  st = wave_sum(st);
  sq = wave_sum(sq);
  float dt = fmaxf(sqrtf(st), EPSN);
  float dq = fmaxf(sqrtf(sq), EPSN);
  float zi = zinv[row];
  float lp = 0.f;
#pragma unroll
  for (int i = 0; i < 8; ++i) {
    int k = i * 64 + lane;
    out_zq[(size_t)row * DIM + k] = tl[i] / dt;
    float e = ql[i] / dq - zl[i] * zi;
    lp += e * e;
  }
  lp = wave_sum(lp);
  if (lane == 0) red[threadIdx.x >> 6] = lp;
  __syncthreads();
  if (threadIdx.x == 0) lpart[blockIdx.x] = red[0] + red[1] + red[2] + red[3];
}

// single block: loss scalar (sum of block partials) + perplexity from counts
__global__ __launch_bounds__(256) void scalars_kernel(
    const float* __restrict__ counts, const float* __restrict__ lpart,
    int ne, int nblk, float inv_n, float inv_total,
    float* __restrict__ out_loss, float* __restrict__ out_perp) {
  __shared__ float red[8];
  int tid = threadIdx.x;
  float s = 0.f;
  for (int jj = tid; jj < ne; jj += 256) {
    float p = counts[jj] * inv_n;
    s += p * logf(p + 1e-10f);
  }
  float l = 0.f;
  for (int jj = tid; jj < nblk; jj += 256) l += lpart[jj];
  s = wave_sum(s);
  l = wave_sum(l);
  if ((tid & 63) == 0) { red[tid >> 6] = s; red[4 + (tid >> 6)] = l; }
  __syncthreads();
  if (tid == 0) {
    float t = red[0] + red[1] + red[2] + red[3];
    float lt = red[4] + red[5] + red[6] + red[7];
    *out_perp = expf(-t);
    *out_loss = 1.25f * lt * inv_total;  // (1+BETA)*mean, sg() identity fwd
  }
}

extern "C" void kernel_launch(void* const* d_in, const int* in_sizes, int n_in,
                              void* d_out, int out_size, void* d_ws, size_t ws_size,
                              hipStream_t stream) {
  const float* z = (const float*)d_in[0];
  const float* emb = (const float*)d_in[1];
  float* out = (float*)d_out;
  float* ws = (float*)d_ws;

  const int nrows = in_sizes[0] / DIM;  // 32768
  const int ne = in_sizes[1] / DIM;     // 8192
  const int nfin = nrows / 4;           // finalize blocks

  // workspace layout (floats)
  float2* eepair = (float2*)ws;                  // ne float2
  float* zinv = ws + 2 * ne;                     // nrows
  int* idxw = (int*)(ws + 2 * ne + nrows);       // nrows
  float* counts = ws + 2 * ne + 2 * nrows;       // ne
  float* lpart = counts + ne;                    // nfin
  _Float16* swz = (_Float16*)(lpart + nfin);     // ne*1024 f16 (~16.8 MB)

  float* out_zq = out + 1;
  float* out_idx = out + 1 + (size_t)nrows * DIM;
  float* out_perp = out + (size_t)out_size - 1;

  hipMemsetAsync(counts, 0, ne * sizeof(float), stream);
  emb_norm_kernel<<<ne / 4, 256, 0, stream>>>(emb, eepair);
  z_norm_kernel<<<nrows / 4, 256, 0, stream>>>(z, zinv);
  emb_split_kernel<<<ne * 64 / 256, 256, 0, stream>>>(emb, swz);
  dist_argmin_kernel<<<nrows / 128, 256, 0, stream>>>(z, swz, eepair, zinv, ne,
                                                      idxw, counts, out_idx);
  finalize_rows_kernel<<<nfin, 256, 0, stream>>>(z, emb, idxw, zinv,
                                                 out_zq, lpart);
  scalars_kernel<<<1, 256, 0, stream>>>(counts, lpart, ne, nfin,
                                        1.0f / (float)nrows,
                                        1.0f / (float)((size_t)nrows * DIM),
                                        out, out_perp);
}